// Round 1
// baseline (1376.379 us; speedup 1.0000x reference)
//
#include <hip/hip_runtime.h>

typedef __bf16 bf16x8 __attribute__((ext_vector_type(8)));
typedef float  f32x4  __attribute__((ext_vector_type(4)));

#define NB 64      // attention tokens (B axis)
#define NC 512     // channels
#define NL 4096    // batched positions (L axis)
#define LT 16      // l-tile per workgroup: one 64B line per (b,c) row

// LDS regions, aliased in time (max 128 KiB):
//   phase1 stage: bf16 [LT][64 m][40 cc]  (cc 32 padded->40 to break b128 bank conflicts) = 81920 B
//   P' matrix   : bf16 [LT][64 n][64 m]                                                  = 131072 B
//   phase2 stage: bf16 [32 cc][1032]      (per-cc block 16*64 padded +8)                 = 66048 B

__global__ __launch_bounds__(512, 2)
void attn_prop_kernel(const float* __restrict__ x, float* __restrict__ out)
{
    __shared__ __align__(16) unsigned char smem_raw[131072];
    __bf16* const p_lds = (__bf16*)smem_raw;
    __bf16* const s1    = (__bf16*)smem_raw;
    __bf16* const s2    = (__bf16*)smem_raw;

    const int tid  = threadIdx.x;
    const int wave = tid >> 6;
    const int lane = tid & 63;
    const int quad = lane >> 4;
    const int c16  = lane & 15;
    const int l0   = blockIdx.x * LT;

    // ================= phase 1: S = (A A^T)/sqrt(C); P' = softmax(S) + I ==========
    // wave w owns l = 2w, 2w+1. acc[ll][i][j] = 16x16 tile (rows 16i, cols 16j).
    f32x4 acc[2][4][4];
#pragma unroll
    for (int ll = 0; ll < 2; ++ll)
#pragma unroll
        for (int i = 0; i < 4; ++i)
#pragma unroll
            for (int j = 0; j < 4; ++j)
                acc[ll][i][j] = (f32x4){0.f, 0.f, 0.f, 0.f};

    for (int kc = 0; kc < 16; ++kc) {
        const int c0 = kc * 32;
        __syncthreads();   // prev iter frag reads done before restage
#pragma unroll
        for (int r = 0; r < 4; ++r) {
            const int m  = (tid >> 5) + (r << 4);
            const int cc = tid & 31;
            const float* src = x + ((m * NC + c0 + cc) * NL + l0);
            union { float4 q[4]; float f[16]; } u;
            u.q[0] = ((const float4*)src)[0];
            u.q[1] = ((const float4*)src)[1];
            u.q[2] = ((const float4*)src)[2];
            u.q[3] = ((const float4*)src)[3];
#pragma unroll
            for (int l = 0; l < 16; ++l)
                s1[(l * 64 + m) * 40 + cc] = (__bf16)u.f[l];
        }
        __syncthreads();
#pragma unroll
        for (int ll = 0; ll < 2; ++ll) {
            const int l = wave * 2 + ll;
            bf16x8 a[4];
#pragma unroll
            for (int i = 0; i < 4; ++i)
                a[i] = *(const bf16x8*)(s1 + (l * 64 + i * 16 + c16) * 40 + quad * 8);
            // B-fragment of A^T (tile j) == A-fragment of A (tile j)
#pragma unroll
            for (int i = 0; i < 4; ++i)
#pragma unroll
                for (int j = 0; j < 4; ++j)
                    acc[ll][i][j] = __builtin_amdgcn_mfma_f32_16x16x32_bf16(
                        a[i], a[j], acc[ll][i][j], 0, 0, 0);
        }
    }
    __syncthreads();   // all frag reads of s1 done; safe to overwrite with P'

    // softmax rows n = 16i + 4*quad + q; cols m = 16j + c16 (j in-lane, c16 across quad)
    const float rs = 0.04419417382415922f;   // 1/sqrt(512)
#pragma unroll
    for (int ll = 0; ll < 2; ++ll) {
        const int l = wave * 2 + ll;
#pragma unroll
        for (int i = 0; i < 4; ++i) {
#pragma unroll
            for (int q = 0; q < 4; ++q) {
                float s[4];
#pragma unroll
                for (int j = 0; j < 4; ++j) s[j] = acc[ll][i][j][q] * rs;
                float rmax = fmaxf(fmaxf(s[0], s[1]), fmaxf(s[2], s[3]));
#pragma unroll
                for (int d = 1; d <= 8; d <<= 1)
                    rmax = fmaxf(rmax, __shfl_xor(rmax, d, 64));
                float e[4], rsum = 0.f;
#pragma unroll
                for (int j = 0; j < 4; ++j) { e[j] = __expf(s[j] - rmax); rsum += e[j]; }
#pragma unroll
                for (int d = 1; d <= 8; d <<= 1)
                    rsum += __shfl_xor(rsum, d, 64);
                const float inv = 1.0f / rsum;
                const int n = i * 16 + quad * 4 + q;
#pragma unroll
                for (int j = 0; j < 4; ++j) {
                    float p = e[j] * inv;
                    if (i == j && (quad * 4 + q) == c16) p += 1.0f;  // P' = P + I (residual)
                    p_lds[l * 4096 + n * 64 + j * 16 + c16] = (__bf16)p;
                }
            }
        }
    }
    __syncthreads();

    // phase-2 wave assignment: wave -> (n-tile iw, c-subtile jw), all 16 l per wave.
    const int iw = wave & 3;
    const int jw = wave >> 2;
    bf16x8 pf[16][2];   // P' A-fragments: P'[n=16iw+c16][m = kc*32 + quad*8 + j]
#pragma unroll
    for (int l = 0; l < 16; ++l)
#pragma unroll
        for (int k2 = 0; k2 < 2; ++k2)
            pf[l][k2] = *(const bf16x8*)(p_lds + l * 4096 + (iw * 16 + c16) * 64 + k2 * 32 + quad * 8);
    __syncthreads();   // pf loaded; s2 may overwrite P' region

    // ================= phase 2: out = P' A (chunked over c) =======================
    for (int ch = 0; ch < 16; ++ch) {
        const int c0 = ch * 32;
#pragma unroll
        for (int r = 0; r < 4; ++r) {
            const int m  = tid & 63;
            const int cc = (tid >> 6) + (r << 3);
            const float* src = x + ((m * NC + c0 + cc) * NL + l0);
            union { float4 q[4]; float f[16]; } u;
            u.q[0] = ((const float4*)src)[0];
            u.q[1] = ((const float4*)src)[1];
            u.q[2] = ((const float4*)src)[2];
            u.q[3] = ((const float4*)src)[3];
#pragma unroll
            for (int l = 0; l < 16; ++l)
                s2[cc * 1032 + l * 64 + m] = (__bf16)u.f[l];
        }
        __syncthreads();

        f32x4 acc2[16];
#pragma unroll
        for (int l = 0; l < 16; ++l) {
            f32x4 a2 = (f32x4){0.f, 0.f, 0.f, 0.f};
#pragma unroll
            for (int k2 = 0; k2 < 2; ++k2) {
                bf16x8 b = *(const bf16x8*)(s2 + (jw * 16 + c16) * 1032 + l * 64 + k2 * 32 + quad * 8);
                a2 = __builtin_amdgcn_mfma_f32_16x16x32_bf16(pf[l][k2], b, a2, 0, 0, 0);
            }
            acc2[l] = a2;
        }

        // write: lane owns rows n = 16iw+4quad+q, col cg, all 16 l -> 4 float4 per row
        const int cg = c0 + jw * 16 + c16;
#pragma unroll
        for (int q = 0; q < 4; ++q) {
            const int n = iw * 16 + quad * 4 + q;
            float* dst = out + ((n * NC + cg) * NL + l0);
            float4 w;
            w.x = acc2[0][q];  w.y = acc2[1][q];  w.z = acc2[2][q];  w.w = acc2[3][q];
            ((float4*)dst)[0] = w;
            w.x = acc2[4][q];  w.y = acc2[5][q];  w.z = acc2[6][q];  w.w = acc2[7][q];
            ((float4*)dst)[1] = w;
            w.x = acc2[8][q];  w.y = acc2[9][q];  w.z = acc2[10][q]; w.w = acc2[11][q];
            ((float4*)dst)[2] = w;
            w.x = acc2[12][q]; w.y = acc2[13][q]; w.z = acc2[14][q]; w.w = acc2[15][q];
            ((float4*)dst)[3] = w;
        }
        __syncthreads();   // B-frag reads done before next restage
    }
}

extern "C" void kernel_launch(void* const* d_in, const int* in_sizes, int n_in,
                              void* d_out, int out_size, void* d_ws, size_t ws_size,
                              hipStream_t stream)
{
    const float* x = (const float*)d_in[0];
    float* o = (float*)d_out;
    attn_prop_kernel<<<dim3(NL / LT), dim3(512), 0, stream>>>(x, o);
}